// Round 4
// baseline (698.155 us; speedup 1.0000x reference)
//
#include <hip/hip_runtime.h>

// Problem constants (from reference setup_inputs)
#define DIN 200     // K
#define DH  100     // J
#define NJT 7       // j tiles of 16 (112, padded)
#define NKT 7       // k tiles of 32 (224, padded)
#define MARGIN 2e-3f

typedef _Float16 half8 __attribute__((ext_vector_type(8)));
typedef float f32x4 __attribute__((ext_vector_type(4)));

__device__ inline double wave_sum_f64(double v) {
#pragma unroll
  for (int m = 1; m < 64; m <<= 1) v += __shfl_xor(v, m, 64);
  return v;
}

// Exact-sign fp64 recompute of one row's delta (wave-cooperative). Rare path.
__device__ double fp64_delta_row(const float* __restrict__ x,
                                 const float* __restrict__ w_out,
                                 const float* __restrict__ b_out,
                                 const float* __restrict__ w_cat,
                                 const float* __restrict__ b_cat,
                                 int row, int lane) {
  const float* xr = x + (size_t)row * DIN;
  const int j0 = lane, j1 = lane + 64;
  double a0 = 0.0, a1 = 0.0;
#pragma unroll 4
  for (int k = 0; k < DIN; ++k) {
    double xd = (double)xr[k];
    a0 += xd * (double)w_out[j0 * DIN + k];
    if (j1 < DH) a1 += xd * (double)w_out[j1 * DIN + k];
  }
  double t = 0.0;
  {
    double u = a0 + (double)b_out[j0];
    if (u > 0.0) t += u * ((double)w_cat[j0] - (double)w_cat[DH + j0]);
  }
  if (j1 < DH) {
    double u = a1 + (double)b_out[j1];
    if (u > 0.0) t += u * ((double)w_cat[j1] - (double)w_cat[DH + j1]);
  }
  t = wave_sum_f64(t);
  return t + ((double)b_cat[0] - (double)b_cat[1]);
}

__device__ inline half8 cvt8(float4 u, float4 v) {
  half8 h;
  h[0] = (_Float16)u.x; h[1] = (_Float16)u.y;
  h[2] = (_Float16)u.z; h[3] = (_Float16)u.w;
  h[4] = (_Float16)v.x; h[5] = (_Float16)v.y;
  h[6] = (_Float16)v.z; h[7] = (_Float16)v.w;
  return h;
}

__global__ __launch_bounds__(256, 3)
void entmax_sign_mfma(const float* __restrict__ x,
                      const float* __restrict__ w_out,
                      const float* __restrict__ b_out,
                      const float* __restrict__ w_cat,
                      const float* __restrict__ b_cat,
                      const float* __restrict__ w2,
                      const float* __restrict__ b2,
                      float* __restrict__ out, int N) {
  // Fragment-ordered f16 B (w_out^T): frag (jt,kt), lane l holds
  // w_out[jt*16+(l&15)][kt*32+(l>>4)*8 + 0..7]. 49 frags x 1 KB. 0 bank conflicts.
  __shared__ _Float16 wlds[NJT * NKT * 512];
  __shared__ float bb_s[NJT * 16];   // b_out padded to 112
  __shared__ float dd_s[NJT * 16];   // dw = w_cat[0]-w_cat[1] padded

  const int tid  = threadIdx.x;
  const int lane = tid & 63;
  const int wid  = tid >> 6;

  // ---- stage B fragments (once per block; w_out is L2/L3-resident) ----
  for (int t = tid; t < NJT * NKT * 64; t += 256) {
    const int f  = t >> 6, l = t & 63;
    const int jt = f / NKT, kt = f - jt * NKT;
    const int j  = jt * 16 + (l & 15);
    const int k  = kt * 32 + (l >> 4) * 8;
    half8 h = {};
    if (j < DH && k < DIN) {
      float4 a = *(const float4*)(w_out + j * DIN + k);
      float4 b = *(const float4*)(w_out + j * DIN + k + 4);
      h = cvt8(a, b);
    }
    *(half8*)(&wlds[f * 512 + l * 8]) = h;
  }
  for (int t = tid; t < NJT * 16; t += 256) {
    bb_s[t] = (t < DH) ? b_out[t] : 0.f;
    dd_s[t] = (t < DH) ? (w_cat[t] - w_cat[DH + t]) : 0.f;
  }
  __syncthreads();

  const float db = b_cat[0] - b_cat[1];
  const float c0 = w2[0] + b2[0];
  const float c1 = w2[1] + b2[0];

  const int arow = lane & 15;        // A-frag row within 16-row group
  const int qid  = lane >> 4;        // quad id
  const int koff = qid * 8;          // k sub-offset within 32-k tile
  const long long wave = (long long)blockIdx.x * 4 + wid;
  const float* xw = x + (size_t)(wave * 128 + arow) * DIN + koff;

  // ---- prologue: loads for group 0 (14 x dwordx4 per lane max) ----
  float4 u[NKT], v[NKT];
#pragma unroll
  for (int kt = 0; kt < NKT; ++kt) {
    if (kt * 32 + koff < DIN) {      // only kt=6 is partially valid (quad 0)
      u[kt] = *(const float4*)(xw + kt * 32);
      v[kt] = *(const float4*)(xw + kt * 32 + 4);
    }
  }

#pragma unroll 1
  for (int g = 0; g < 8; ++g) {
    // convert current group's x to f16 A-frags (waits on loads here)
    half8 a[NKT];
#pragma unroll
    for (int kt = 0; kt < NKT; ++kt)
      a[kt] = (kt * 32 + koff < DIN) ? cvt8(u[kt], v[kt]) : (half8){};

    // issue next group's loads; latency hidden under the MFMA phase below
    if (g < 7) {
      const float* xn = xw + (size_t)(g + 1) * 16 * DIN;
#pragma unroll
      for (int kt = 0; kt < NKT; ++kt) {
        if (kt * 32 + koff < DIN) {
          u[kt] = *(const float4*)(xn + kt * 32);
          v[kt] = *(const float4*)(xn + kt * 32 + 4);
        }
      }
    }

    f32x4 acc[NJT];
#pragma unroll
    for (int jt = 0; jt < NJT; ++jt) acc[jt] = (f32x4){0.f, 0.f, 0.f, 0.f};

    // kt outer / jt inner: 7 independent accumulation chains
#pragma unroll
    for (int kt = 0; kt < NKT; ++kt)
#pragma unroll
      for (int jt = 0; jt < NJT; ++jt) {
        half8 bf = *(half8*)(&wlds[(jt * NKT + kt) * 512 + lane * 8]);
        acc[jt] = __builtin_amdgcn_mfma_f32_16x16x32_f16(a[kt], bf, acc[jt], 0, 0, 0);
      }

    // ---- epilogue: relu + dw-weight, 16-lane j-reduce, decide, store ----
    const int rbase = (int)(wave * 128) + g * 16;
    float part[4] = {0.f, 0.f, 0.f, 0.f};
#pragma unroll
    for (int jt = 0; jt < NJT; ++jt) {
      const float bj = bb_s[jt * 16 + arow];
      const float dj = dd_s[jt * 16 + arow];
#pragma unroll
      for (int r = 0; r < 4; ++r)
        part[r] += fmaxf(acc[jt][r] + bj, 0.f) * dj;
    }
#pragma unroll
    for (int m = 1; m < 16; m <<= 1)
#pragma unroll
      for (int r = 0; r < 4; ++r)
        part[r] += __shfl_xor(part[r], m, 64);

    f32x4 res;
    unsigned rowmask = 0;
#pragma unroll
    for (int r = 0; r < 4; ++r) {
      const float delta = part[r] + db;
      res[r] = (delta >= 0.f) ? c0 : c1;
      unsigned long long bl = __ballot((fabsf(delta) < MARGIN) && arow == 0);
      rowmask |= (unsigned)((bl >>  0) & 1ull) << (0 + r);   // quad 0 -> rows 0..3
      rowmask |= (unsigned)((bl >> 16) & 1ull) << (4 + r);   // quad 1 -> rows 4..7
      rowmask |= (unsigned)((bl >> 32) & 1ull) << (8 + r);   // quad 2 -> rows 8..11
      rowmask |= (unsigned)((bl >> 48) & 1ull) << (12 + r);  // quad 3 -> rows 12..15
    }
    if (arow == 0) *(f32x4*)(&out[rbase + qid * 4]) = res;

    // ---- rare exact-sign fallback (wave-uniform loop over flagged rows) ----
    while (rowmask) {
      const int b = __ffs(rowmask) - 1;
      rowmask &= rowmask - 1;
      const int row = rbase + b;
      const double s = fp64_delta_row(x, w_out, b_out, w_cat, b_cat, row, lane);
      if (lane == 0) out[row] = (s >= 0.0) ? c0 : c1;
    }
  }
}

extern "C" void kernel_launch(void* const* d_in, const int* in_sizes, int n_in,
                              void* d_out, int out_size, void* d_ws, size_t ws_size,
                              hipStream_t stream) {
  const float* x     = (const float*)d_in[0];
  const float* w_out = (const float*)d_in[1];
  const float* b_out = (const float*)d_in[2];
  const float* w_cat = (const float*)d_in[3];
  const float* b_cat = (const float*)d_in[4];
  const float* w2    = (const float*)d_in[5];
  const float* b2    = (const float*)d_in[6];
  float* out = (float*)d_out;

  const int N = in_sizes[0] / DIN;     // 524288
  const int nblk = N / 512;            // 1024 blocks; 4 waves x 128 rows each
  entmax_sign_mfma<<<nblk, 256, 0, stream>>>(x, w_out, b_out, w_cat, b_cat,
                                             w2, b2, out, N);
}

// Round 5
// 525.493 us; speedup vs baseline: 1.3286x; 1.3286x over previous
//
#include <hip/hip_runtime.h>

// Problem constants (from reference setup_inputs)
#define DIN 200     // K
#define DH  100     // J
#define NJT 7       // j tiles of 16 (112, padded)
#define NKT 7       // k tiles of 32 (224, padded)
#define MARGIN 2e-3f

typedef _Float16 half8 __attribute__((ext_vector_type(8)));
typedef float f32x4 __attribute__((ext_vector_type(4)));

__device__ inline double wave_sum_f64(double v) {
#pragma unroll
  for (int m = 1; m < 64; m <<= 1) v += __shfl_xor(v, m, 64);
  return v;
}

// Exact-sign fp64 recompute of one row's delta (wave-cooperative). Cold path,
// runs AFTER the main loop so its pressure can't interleave with hot state.
__device__ double fp64_delta_row(const float* __restrict__ x,
                                 const float* __restrict__ w_out,
                                 const float* __restrict__ b_out,
                                 const float* __restrict__ w_cat,
                                 const float* __restrict__ b_cat,
                                 int row, int lane) {
  const float* xr = x + (size_t)row * DIN;
  const int j0 = lane, j1 = lane + 64;
  double a0 = 0.0, a1 = 0.0;
#pragma unroll 4
  for (int k = 0; k < DIN; ++k) {
    double xd = (double)xr[k];
    a0 += xd * (double)w_out[j0 * DIN + k];
    if (j1 < DH) a1 += xd * (double)w_out[j1 * DIN + k];
  }
  double t = 0.0;
  {
    double u = a0 + (double)b_out[j0];
    if (u > 0.0) t += u * ((double)w_cat[j0] - (double)w_cat[DH + j0]);
  }
  if (j1 < DH) {
    double u = a1 + (double)b_out[j1];
    if (u > 0.0) t += u * ((double)w_cat[j1] - (double)w_cat[DH + j1]);
  }
  t = wave_sum_f64(t);
  return t + ((double)b_cat[0] - (double)b_cat[1]);
}

__device__ inline half8 cvt8(float4 u, float4 v) {
  half8 h;
  h[0] = (_Float16)u.x; h[1] = (_Float16)u.y;
  h[2] = (_Float16)u.z; h[3] = (_Float16)u.w;
  h[4] = (_Float16)v.x; h[5] = (_Float16)v.y;
  h[6] = (_Float16)v.z; h[7] = (_Float16)v.w;
  return h;
}

__global__ __launch_bounds__(256, 3)
void entmax_sign_mfma(const float* __restrict__ x,
                      const float* __restrict__ w_out,
                      const float* __restrict__ b_out,
                      const float* __restrict__ w_cat,
                      const float* __restrict__ b_cat,
                      const float* __restrict__ w2,
                      const float* __restrict__ b2,
                      float* __restrict__ out, int N) {
  // Fragment-ordered f16 B (w_out^T): frag (jt,kt), lane l holds
  // w_out[jt*16+(l&15)][kt*32+(l>>4)*8 + 0..7]. 49 frags x 1 KB. 0 bank conflicts.
  __shared__ _Float16 wlds[NJT * NKT * 512];

  const int tid  = threadIdx.x;
  const int lane = tid & 63;
  const int wid  = tid >> 6;

  // ---- stage B fragments (once per block; w_out is L2/L3-resident) ----
  for (int t = tid; t < NJT * NKT * 64; t += 256) {
    const int f  = t >> 6, l = t & 63;
    const int jt = f / NKT, kt = f - jt * NKT;
    const int j  = jt * 16 + (l & 15);
    const int k  = kt * 32 + (l >> 4) * 8;
    half8 h = {};
    if (j < DH && k < DIN) {
      float4 a = *(const float4*)(w_out + j * DIN + k);
      float4 b = *(const float4*)(w_out + j * DIN + k + 4);
      h = cvt8(a, b);
    }
    *(half8*)(&wlds[f * 512 + l * 8]) = h;
  }
  __syncthreads();

  const float db = b_cat[0] - b_cat[1];
  const float c0 = w2[0] + b2[0];
  const float c1 = w2[1] + b2[0];

  const int arow = lane & 15;        // A-frag row within 16-row group (= x row)
  const int qid  = lane >> 4;        // quad id
  const int koff = qid * 8;          // k sub-offset within 32-k tile

  // Per-lane j-epilogue params (g-invariant, hoisted to 14 VGPRs):
  // D-layout: col = lane&15 = j within tile.
  float bj[NJT], dj[NJT];
#pragma unroll
  for (int jt = 0; jt < NJT; ++jt) {
    const int j = jt * 16 + arow;
    bj[jt] = (j < DH) ? b_out[j] : 0.f;
    dj[jt] = (j < DH) ? (w_cat[j] - w_cat[DH + j]) : 0.f;
  }

  const long long wave = (long long)blockIdx.x * 4 + wid;
  const size_t rowbase = (size_t)wave * 128;
  const float* xw = x + (rowbase + arow) * DIN + koff;

  unsigned long long rmask0 = 0ull, rmask1 = 0ull;  // flagged rows (128 bits)

#pragma unroll 1
  for (int g = 0; g < 8; ++g) {
    const float* xp = xw + (size_t)g * 16 * DIN;

    f32x4 acc[NJT];
#pragma unroll
    for (int jt = 0; jt < NJT; ++jt) acc[jt] = (f32x4){0.f, 0.f, 0.f, 0.f};

    // ---- streamed kt with named 2-deep double-buffer (16 VGPRs) ----
    float4 ua, va, ub, vb;
    ua = *(const float4*)(xp + 0);   va = *(const float4*)(xp + 4);    // kt0
    ub = *(const float4*)(xp + 32);  vb = *(const float4*)(xp + 36);   // kt1

#define MFMA_STEP(KT, AF)                                                  \
    {                                                                      \
      const half8 af_ = (AF);                                              \
      _Pragma("unroll")                                                    \
      for (int jt = 0; jt < NJT; ++jt) {                                   \
        half8 bf = *(half8*)(&wlds[(jt * NKT + (KT)) * 512 + lane * 8]);   \
        acc[jt] = __builtin_amdgcn_mfma_f32_16x16x32_f16(af_, bf, acc[jt], \
                                                         0, 0, 0);         \
      }                                                                    \
    }

    { half8 a = cvt8(ua, va);                                   // kt0
      ua = *(const float4*)(xp + 64);  va = *(const float4*)(xp + 68);   // ld kt2
      MFMA_STEP(0, a); }
    { half8 a = cvt8(ub, vb);                                   // kt1
      ub = *(const float4*)(xp + 96);  vb = *(const float4*)(xp + 100);  // ld kt3
      MFMA_STEP(1, a); }
    { half8 a = cvt8(ua, va);                                   // kt2
      ua = *(const float4*)(xp + 128); va = *(const float4*)(xp + 132);  // ld kt4
      MFMA_STEP(2, a); }
    { half8 a = cvt8(ub, vb);                                   // kt3
      ub = *(const float4*)(xp + 160); vb = *(const float4*)(xp + 164);  // ld kt5
      MFMA_STEP(3, a); }
    { half8 a = cvt8(ua, va);                                   // kt4
      if (koff < 8) {                       // kt6 valid only for quad 0
        ua = *(const float4*)(xp + 192); va = *(const float4*)(xp + 196);
      }
      MFMA_STEP(4, a); }
    { half8 a = cvt8(ub, vb);                                   // kt5
      MFMA_STEP(5, a); }
    { half8 a = (koff < 8) ? cvt8(ua, va) : (half8){};          // kt6
      MFMA_STEP(6, a); }
#undef MFMA_STEP

    // ---- epilogue: relu + dw-weight, j-reduce within quad, decide ----
    float part[4] = {0.f, 0.f, 0.f, 0.f};
#pragma unroll
    for (int jt = 0; jt < NJT; ++jt)
#pragma unroll
      for (int r = 0; r < 4; ++r)
        part[r] += fmaxf(acc[jt][r] + bj[jt], 0.f) * dj[jt];
#pragma unroll
    for (int m = 1; m < 16; m <<= 1)
#pragma unroll
      for (int r = 0; r < 4; ++r)
        part[r] += __shfl_xor(part[r], m, 64);

    const int rbase = (int)rowbase + g * 16;   // row = rbase + qid*4 + r
    f32x4 res;
    unsigned gm = 0;
#pragma unroll
    for (int r = 0; r < 4; ++r) {
      const float delta = part[r] + db;
      res[r] = (delta >= 0.f) ? c0 : c1;
      unsigned long long bl = __ballot((fabsf(delta) < MARGIN) && arow == 0);
      gm |= (unsigned)((bl >>  0) & 1ull) << (0 + r);
      gm |= (unsigned)((bl >> 16) & 1ull) << (4 + r);
      gm |= (unsigned)((bl >> 32) & 1ull) << (8 + r);
      gm |= (unsigned)((bl >> 48) & 1ull) << (12 + r);
    }
    if (arow == 0) *(f32x4*)(&out[rbase + qid * 4]) = res;

    if (g < 4) rmask0 |= (unsigned long long)gm << (g * 16);
    else       rmask1 |= (unsigned long long)gm << ((g - 4) * 16);
  }

  // ---- rare exact-sign fallback (cold, after all hot state is dead) ----
#pragma unroll 1
  for (int h = 0; h < 2; ++h) {
    unsigned long long m = h ? rmask1 : rmask0;
    while (m) {
      const int b = __ffsll(m) - 1;
      m &= m - 1;
      const int row = (int)rowbase + h * 64 + b;
      const double s = fp64_delta_row(x, w_out, b_out, w_cat, b_cat, row, lane);
      if (lane == 0) out[row] = (s >= 0.0) ? c0 : c1;
    }
  }
}

extern "C" void kernel_launch(void* const* d_in, const int* in_sizes, int n_in,
                              void* d_out, int out_size, void* d_ws, size_t ws_size,
                              hipStream_t stream) {
  const float* x     = (const float*)d_in[0];
  const float* w_out = (const float*)d_in[1];
  const float* b_out = (const float*)d_in[2];
  const float* w_cat = (const float*)d_in[3];
  const float* b_cat = (const float*)d_in[4];
  const float* w2    = (const float*)d_in[5];
  const float* b2    = (const float*)d_in[6];
  float* out = (float*)d_out;

  const int N = in_sizes[0] / DIN;     // 524288
  const int nblk = N / 512;            // 1024 blocks; 4 waves x 128 rows each
  entmax_sign_mfma<<<nblk, 256, 0, stream>>>(x, w_out, b_out, w_cat, b_cat,
                                             w2, b2, out, N);
}

// Round 6
// 489.623 us; speedup vs baseline: 1.4259x; 1.0733x over previous
//
#include <hip/hip_runtime.h>

// Problem constants (from reference setup_inputs)
#define DIN 200     // K
#define DH  100     // J
#define NJT 7       // j tiles of 16 (112, padded)
#define NKT 7       // k tiles of 32 (224, padded)
#define MARGIN 2e-3f

typedef _Float16 half8 __attribute__((ext_vector_type(8)));
typedef float f32x4 __attribute__((ext_vector_type(4)));

__device__ inline half8 cvt8(float4 u, float4 v) {
  half8 h;
  h[0] = (_Float16)u.x; h[1] = (_Float16)u.y;
  h[2] = (_Float16)u.z; h[3] = (_Float16)u.w;
  h[4] = (_Float16)v.x; h[5] = (_Float16)v.y;
  h[6] = (_Float16)v.z; h[7] = (_Float16)v.w;
  return h;
}

// ---------------- hot kernel: pure f16-MFMA GEMM sign ----------------
template <bool HAVE_WS>
__global__ __launch_bounds__(256, 3)
void entmax_sign_mfma(const float* __restrict__ x,
                      const float* __restrict__ w_out,
                      const float* __restrict__ b_out,
                      const float* __restrict__ w_cat,
                      const float* __restrict__ b_cat,
                      const float* __restrict__ w2,
                      const float* __restrict__ b2,
                      float* __restrict__ out,
                      float* __restrict__ dws) {
  // Fragment-ordered f16 B (w_out^T): frag (jt,kt), lane l holds
  // w_out[jt*16+(l&15)][kt*32+(l>>4)*8 + 0..7]. 49 frags x 1 KB. 0 bank conflicts.
  __shared__ _Float16 wlds[NJT * NKT * 512];

  const int tid  = threadIdx.x;
  const int lane = tid & 63;
  const int wid  = tid >> 6;

  // ---- stage B fragments (once per block; w_out is L2/L3-resident) ----
  for (int t = tid; t < NJT * NKT * 64; t += 256) {
    const int f  = t >> 6, l = t & 63;
    const int jt = f / NKT, kt = f - jt * NKT;
    const int j  = jt * 16 + (l & 15);
    const int k  = kt * 32 + (l >> 4) * 8;
    half8 h = {};
    if (j < DH && k < DIN) {
      float4 a = *(const float4*)(w_out + j * DIN + k);
      float4 b = *(const float4*)(w_out + j * DIN + k + 4);
      h = cvt8(a, b);
    }
    *(half8*)(&wlds[f * 512 + l * 8]) = h;
  }
  __syncthreads();

  const float db = b_cat[0] - b_cat[1];
  const float c0 = w2[0] + b2[0];
  const float c1 = w2[1] + b2[0];

  const int arow = lane & 15;        // A-frag row within 16-row group (= x row)
  const int qid  = lane >> 4;        // quad id
  const int koff = qid * 8;          // k sub-offset within 32-k tile

  // Per-lane j-epilogue params (g-invariant): D-layout col = lane&15.
  float bj[NJT], dj[NJT];
#pragma unroll
  for (int jt = 0; jt < NJT; ++jt) {
    const int j = jt * 16 + arow;
    bj[jt] = (j < DH) ? b_out[j] : 0.f;
    dj[jt] = (j < DH) ? (w_cat[j] - w_cat[DH + j]) : 0.f;
  }

  const long long wave = (long long)blockIdx.x * 4 + wid;
  const size_t rowbase = (size_t)wave * 128;
  const float* xw = x + (rowbase + arow) * DIN + koff;

#pragma unroll 1
  for (int g = 0; g < 8; ++g) {
    const float* xp = xw + (size_t)g * 16 * DIN;

    f32x4 acc[NJT];
#pragma unroll
    for (int jt = 0; jt < NJT; ++jt) acc[jt] = (f32x4){0.f, 0.f, 0.f, 0.f};

    // ---- streamed kt with named 2-deep double-buffer ----
    float4 ua, va, ub, vb;
    ua = *(const float4*)(xp + 0);   va = *(const float4*)(xp + 4);    // kt0
    ub = *(const float4*)(xp + 32);  vb = *(const float4*)(xp + 36);   // kt1

#define MFMA_STEP(KT, AF)                                                  \
    {                                                                      \
      const half8 af_ = (AF);                                              \
      _Pragma("unroll")                                                    \
      for (int jt = 0; jt < NJT; ++jt) {                                   \
        half8 bf = *(half8*)(&wlds[(jt * NKT + (KT)) * 512 + lane * 8]);   \
        acc[jt] = __builtin_amdgcn_mfma_f32_16x16x32_f16(af_, bf, acc[jt], \
                                                         0, 0, 0);         \
      }                                                                    \
    }

    { half8 a = cvt8(ua, va);                                   // kt0
      ua = *(const float4*)(xp + 64);  va = *(const float4*)(xp + 68);   // ld kt2
      MFMA_STEP(0, a); }
    { half8 a = cvt8(ub, vb);                                   // kt1
      ub = *(const float4*)(xp + 96);  vb = *(const float4*)(xp + 100);  // ld kt3
      MFMA_STEP(1, a); }
    { half8 a = cvt8(ua, va);                                   // kt2
      ua = *(const float4*)(xp + 128); va = *(const float4*)(xp + 132);  // ld kt4
      MFMA_STEP(2, a); }
    { half8 a = cvt8(ub, vb);                                   // kt3
      ub = *(const float4*)(xp + 160); vb = *(const float4*)(xp + 164);  // ld kt5
      MFMA_STEP(3, a); }
    { half8 a = cvt8(ua, va);                                   // kt4
      if (koff < 8) {                       // kt6 valid only for quad 0
        ua = *(const float4*)(xp + 192); va = *(const float4*)(xp + 196);
      }
      MFMA_STEP(4, a); }
    { half8 a = cvt8(ub, vb);                                   // kt5
      MFMA_STEP(5, a); }
    { half8 a = (koff < 8) ? cvt8(ua, va) : (half8){};          // kt6
      MFMA_STEP(6, a); }
#undef MFMA_STEP

    // ---- epilogue: relu + dw-weight, 16-lane j-reduce, decide, store ----
    float part[4] = {0.f, 0.f, 0.f, 0.f};
#pragma unroll
    for (int jt = 0; jt < NJT; ++jt)
#pragma unroll
      for (int r = 0; r < 4; ++r)
        part[r] += fmaxf(acc[jt][r] + bj[jt], 0.f) * dj[jt];
#pragma unroll
    for (int m = 1; m < 16; m <<= 1)
#pragma unroll
      for (int r = 0; r < 4; ++r)
        part[r] += __shfl_xor(part[r], m, 64);

    const int rbase = (int)rowbase + g * 16;   // row = rbase + qid*4 + r
    f32x4 res, dlt;
#pragma unroll
    for (int r = 0; r < 4; ++r) {
      const float delta = part[r] + db;
      dlt[r] = delta;
      res[r] = (delta >= 0.f) ? c0 : c1;
    }
    if (arow == 0) {
      *(f32x4*)(&out[rbase + qid * 4]) = res;
      if (HAVE_WS) {
        *(f32x4*)(&dws[rbase + qid * 4]) = dlt;
      } else {
        // Tiny-ws fallback: lane-local exact fp64 fix (cold, improbable path)
#pragma unroll 1
        for (int r = 0; r < 4; ++r) {
          if (fabsf(dlt[r]) < MARGIN) {
            const int row = rbase + qid * 4 + r;
            const float* xr = x + (size_t)row * DIN;
            double s = (double)b_cat[0] - (double)b_cat[1];
            for (int j = 0; j < DH; ++j) {
              double a = (double)b_out[j];
              for (int k = 0; k < DIN; ++k)
                a += (double)xr[k] * (double)w_out[j * DIN + k];
              if (a > 0.0) s += a * ((double)w_cat[j] - (double)w_cat[DH + j]);
            }
            out[row] = (s >= 0.0) ? c0 : c1;
          }
        }
      }
    }
  }
}

// ---------------- cold kernel: exact-sign fixup of near-boundary rows ----------------
__global__ __launch_bounds__(256, 4)
void entmax_fixup(const float* __restrict__ x,
                  const float* __restrict__ w_out,
                  const float* __restrict__ b_out,
                  const float* __restrict__ w_cat,
                  const float* __restrict__ b_cat,
                  const float* __restrict__ w2,
                  const float* __restrict__ b2,
                  float* __restrict__ out,
                  const float* __restrict__ dws) {
  const int tid  = threadIdx.x;
  const int lane = tid & 63;
  const long long wave = (long long)blockIdx.x * 4 + (tid >> 6);
  const int base = (int)(wave * 64);

  const float d = dws[base + lane];
  unsigned long long m = __ballot(fabsf(d) < MARGIN);
  if (!m) return;

  const float c0 = w2[0] + b2[0];
  const float c1 = w2[1] + b2[0];
  const int j0 = lane, j1 = lane + 64;

  while (m) {
    const int b = __ffsll(m) - 1;
    m &= m - 1;
    const int row = base + b;
    const float* xr = x + (size_t)row * DIN;
    double a0 = 0.0, a1 = 0.0;
#pragma unroll 4
    for (int k = 0; k < DIN; ++k) {
      double xd = (double)xr[k];
      a0 += xd * (double)w_out[j0 * DIN + k];
      if (j1 < DH) a1 += xd * (double)w_out[j1 * DIN + k];
    }
    double t = 0.0;
    {
      double u = a0 + (double)b_out[j0];
      if (u > 0.0) t += u * ((double)w_cat[j0] - (double)w_cat[DH + j0]);
    }
    if (j1 < DH) {
      double u = a1 + (double)b_out[j1];
      if (u > 0.0) t += u * ((double)w_cat[j1] - (double)w_cat[DH + j1]);
    }
#pragma unroll
    for (int s = 1; s < 64; s <<= 1) t += __shfl_xor(t, s, 64);
    t += (double)b_cat[0] - (double)b_cat[1];
    if (lane == 0) out[row] = (t >= 0.0) ? c0 : c1;
  }
}

extern "C" void kernel_launch(void* const* d_in, const int* in_sizes, int n_in,
                              void* d_out, int out_size, void* d_ws, size_t ws_size,
                              hipStream_t stream) {
  const float* x     = (const float*)d_in[0];
  const float* w_out = (const float*)d_in[1];
  const float* b_out = (const float*)d_in[2];
  const float* w_cat = (const float*)d_in[3];
  const float* b_cat = (const float*)d_in[4];
  const float* w2    = (const float*)d_in[5];
  const float* b2    = (const float*)d_in[6];
  float* out = (float*)d_out;

  const int N = in_sizes[0] / DIN;     // 524288
  const int nblk = N / 512;            // 1024 blocks; 4 waves x 128 rows each

  if (ws_size >= (size_t)N * sizeof(float)) {
    float* dws = (float*)d_ws;
    entmax_sign_mfma<true><<<nblk, 256, 0, stream>>>(x, w_out, b_out, w_cat,
                                                     b_cat, w2, b2, out, dws);
    entmax_fixup<<<N / 256, 256, 0, stream>>>(x, w_out, b_out, w_cat, b_cat,
                                              w2, b2, out, dws);
  } else {
    entmax_sign_mfma<false><<<nblk, 256, 0, stream>>>(x, w_out, b_out, w_cat,
                                                      b_cat, w2, b2, out, nullptr);
  }
}

// Round 7
// 314.577 us; speedup vs baseline: 2.2193x; 1.5564x over previous
//
#include <hip/hip_runtime.h>

// Problem constants (from reference setup_inputs)
#define DIN 200      // K (floats per x row)
#define DH  100      // J
#define NJT 7        // j tiles of 16 (112, padded)
#define NKT 7        // k tiles of 32 (224, padded)
#define MARGIN 2e-3f // |delta| below this -> exact fp64 fixup (15 sigma of f16 err)
#define NG   16      // 16-row groups per wave (rows/block = 4*NG*16 = 1024)
#define LROW 208     // padded LDS row stride in floats (16*208*4 = 13312 = 13 KiB)
#define CH   13      // global_load_lds 1KB chunks per group (16*LROW*4/1024)
#define GFL  (16 * LROW)      // floats per group buffer
#define WREG (2 * GFL)        // floats per wave region (double buffer)

typedef _Float16 half8 __attribute__((ext_vector_type(8)));
typedef float f32x4 __attribute__((ext_vector_type(4)));

__device__ inline half8 cvt8(float4 u, float4 v) {
  half8 h;
  h[0] = (_Float16)u.x; h[1] = (_Float16)u.y;
  h[2] = (_Float16)u.z; h[3] = (_Float16)u.w;
  h[4] = (_Float16)v.x; h[5] = (_Float16)v.y;
  h[6] = (_Float16)v.z; h[7] = (_Float16)v.w;
  return h;
}

// ---------------- hot kernel: pure f16-MFMA GEMM sign ----------------
template <bool HAVE_WS>
__global__ __launch_bounds__(256)
void entmax_sign_mfma(const float* __restrict__ x,
                      const float* __restrict__ w_out,
                      const float* __restrict__ b_out,
                      const float* __restrict__ w_cat,
                      const float* __restrict__ b_cat,
                      const float* __restrict__ w2,
                      const float* __restrict__ b2,
                      float* __restrict__ out,
                      float* __restrict__ dws) {
  // Per-wave double-buffered x regions (4 waves x 2 x 16 rows x 208 floats)
  __shared__ float xlds[4 * WREG];                 // 106496 B
  // Fragment-ordered f16 B (w_out^T): frag (jt,kt), lane l holds
  // w_out[jt*16+(l&15)][kt*32+(l>>4)*8 + 0..7]. 0 bank conflicts on ds_read_b128.
  __shared__ _Float16 wlds[NJT * NKT * 512];       // 50176 B

  const int tid  = threadIdx.x;
  const int lane = tid & 63;
  const int wid  = tid >> 6;
  const int arow = lane & 15;        // A-frag row within 16-row group
  const int qid  = lane >> 4;        // quad id; koff = qid*8

  // ---- stage B fragments (once per block; w_out is L2-resident) ----
  for (int t = tid; t < NJT * NKT * 64; t += 256) {
    const int f  = t >> 6, l = t & 63;
    const int jt = f / NKT, kt = f - jt * NKT;
    const int j  = jt * 16 + (l & 15);
    const int k  = kt * 32 + (l >> 4) * 8;
    half8 h = {};
    if (j < DH && k < DIN) {
      float4 a = *(const float4*)(w_out + j * DIN + k);
      float4 b = *(const float4*)(w_out + j * DIN + k + 4);
      h = cvt8(a, b);
    }
    *(half8*)(&wlds[f * 512 + l * 8]) = h;
  }

  const float db = b_cat[0] - b_cat[1];
  const float c0 = w2[0] + b2[0];
  const float c1 = w2[1] + b2[0];

  float bj[NJT], dj[NJT];
#pragma unroll
  for (int jt = 0; jt < NJT; ++jt) {
    const int j = jt * 16 + arow;
    bj[jt] = (j < DH) ? b_out[j] : 0.f;
    dj[jt] = (j < DH) ? (w_cat[j] - w_cat[DH + j]) : 0.f;
  }

  const int blockBase = blockIdx.x * (4 * NG * 16);
  float* xw = &xlds[wid * WREG];

  // Stage group g into per-wave buffer buf. LDS dest is linear (wave-uniform
  // base + lane*16); the 208-float row pad is realized by pre-mapping the
  // per-lane GLOBAL source address from the lane's LDS slot (m173 pattern).
  auto stage = [&](int buf, int g) {
    const int gRow0 = blockBase + g * 64 + wid * 16;
#pragma unroll
    for (int c = 0; c < CH; ++c) {
      const int fo  = c * 256 + lane * 4;       // float offset in wave buffer
      const int row = fo / LROW;                // magic-mul div
      const int col = fo - row * LROW;
      const float* src = x + (size_t)(gRow0 + row) * DIN + (col < DIN ? col : 0);
      float* dst = xw + buf * GFL + c * 256;    // wave-uniform
      __builtin_amdgcn_global_load_lds(
          (const __attribute__((address_space(1))) void*)src,
          (__attribute__((address_space(3))) void*)dst, 16, 0, 0);
    }
  };

  stage(0, 0);
  stage(1, 1);
  __syncthreads();   // w-frags visible to all waves; drains groups 0,1 (vmcnt 0)

#pragma unroll 1
  for (int g = 0; g < NG; ++g) {
    // Wait own group-g loads: queue (old->new) = loads(g)[13], stores(g-1)[2],
    // loads(g+1)[13] -> allow 15 newest. Last iter: only stores(g-1) newer -> 2.
    if (g == NG - 1) { asm volatile("s_waitcnt vmcnt(2)" ::: "memory"); }
    else             { asm volatile("s_waitcnt vmcnt(15)" ::: "memory"); }
    __builtin_amdgcn_sched_barrier(0);

    const float* xrow = xw + (g & 1) * GFL + arow * LROW;

    f32x4 acc[NJT];
#pragma unroll
    for (int jt = 0; jt < NJT; ++jt) acc[jt] = (f32x4){0.f, 0.f, 0.f, 0.f};

#pragma unroll
    for (int kt = 0; kt < NKT; ++kt) {
      half8 a = {};
      if (kt < 6 || qid == 0) {    // kt6 cols 192..199 valid only for quad 0
        float4 u = *(const float4*)(xrow + kt * 32 + qid * 8);
        float4 v = *(const float4*)(xrow + kt * 32 + qid * 8 + 4);
        a = cvt8(u, v);
      }
#pragma unroll
      for (int jt = 0; jt < NJT; ++jt) {
        half8 bf = *(half8*)(&wlds[(jt * NKT + kt) * 512 + lane * 8]);
        acc[jt] = __builtin_amdgcn_mfma_f32_16x16x32_f16(a, bf, acc[jt], 0, 0, 0);
      }
    }

    // ---- epilogue: relu + dw-weight, 16-lane j-reduce, decide, store ----
    float part[4] = {0.f, 0.f, 0.f, 0.f};
#pragma unroll
    for (int jt = 0; jt < NJT; ++jt)
#pragma unroll
      for (int r = 0; r < 4; ++r)
        part[r] += fmaxf(acc[jt][r] + bj[jt], 0.f) * dj[jt];
#pragma unroll
    for (int m = 1; m < 16; m <<= 1)
#pragma unroll
      for (int r = 0; r < 4; ++r)
        part[r] += __shfl_xor(part[r], m, 64);

    const int rbase = blockBase + g * 64 + wid * 16;  // row = rbase + qid*4 + r
    f32x4 res, dlt;
#pragma unroll
    for (int r = 0; r < 4; ++r) {
      const float delta = part[r] + db;
      dlt[r] = delta;
      res[r] = (delta >= 0.f) ? c0 : c1;
    }
    if (arow == 0) {
      *(f32x4*)(&out[rbase + qid * 4]) = res;        // store #1
      if (HAVE_WS) {
        *(f32x4*)(&dws[rbase + qid * 4]) = dlt;      // store #2
      } else {
        // Tiny-ws fallback: lane-local exact fp64 fix (cold, improbable path)
#pragma unroll 1
        for (int r = 0; r < 4; ++r) {
          if (fabsf(dlt[r]) < MARGIN) {
            const int row = rbase + qid * 4 + r;
            const float* xr = x + (size_t)row * DIN;
            double s = (double)b_cat[0] - (double)b_cat[1];
            for (int j = 0; j < DH; ++j) {
              double a = (double)b_out[j];
              for (int k = 0; k < DIN; ++k)
                a += (double)xr[k] * (double)w_out[j * DIN + k];
              if (a > 0.0) s += a * ((double)w_cat[j] - (double)w_cat[DH + j]);
            }
            out[row] = (s >= 0.0) ? c0 : c1;
          }
        }
      }
    }

    // My ds_reads are consumed; safe to overwrite buf (g&1) with group g+2.
    asm volatile("s_waitcnt lgkmcnt(0)" ::: "memory");
    __builtin_amdgcn_sched_barrier(0);
    if (g + 2 < NG) stage(g & 1, g + 2);
  }
}

// ---------------- cold kernel: exact-sign fixup of near-boundary rows ----------------
__global__ __launch_bounds__(256, 4)
void entmax_fixup(const float* __restrict__ x,
                  const float* __restrict__ w_out,
                  const float* __restrict__ b_out,
                  const float* __restrict__ w_cat,
                  const float* __restrict__ b_cat,
                  const float* __restrict__ w2,
                  const float* __restrict__ b2,
                  float* __restrict__ out,
                  const float* __restrict__ dws) {
  const int tid  = threadIdx.x;
  const int lane = tid & 63;
  const long long wave = (long long)blockIdx.x * 4 + (tid >> 6);
  const int base = (int)(wave * 64);

  const float d = dws[base + lane];
  unsigned long long m = __ballot(fabsf(d) < MARGIN);
  if (!m) return;

  const float c0 = w2[0] + b2[0];
  const float c1 = w2[1] + b2[0];
  const int j0 = lane, j1 = lane + 64;

  while (m) {
    const int b = __ffsll(m) - 1;
    m &= m - 1;
    const int row = base + b;
    const float* xr = x + (size_t)row * DIN;
    double a0 = 0.0, a1 = 0.0;
#pragma unroll 4
    for (int k = 0; k < DIN; ++k) {
      double xd = (double)xr[k];
      a0 += xd * (double)w_out[j0 * DIN + k];
      if (j1 < DH) a1 += xd * (double)w_out[j1 * DIN + k];
    }
    double t = 0.0;
    {
      double u = a0 + (double)b_out[j0];
      if (u > 0.0) t += u * ((double)w_cat[j0] - (double)w_cat[DH + j0]);
    }
    if (j1 < DH) {
      double u = a1 + (double)b_out[j1];
      if (u > 0.0) t += u * ((double)w_cat[j1] - (double)w_cat[DH + j1]);
    }
#pragma unroll
    for (int s = 1; s < 64; s <<= 1) t += __shfl_xor(t, s, 64);
    t += (double)b_cat[0] - (double)b_cat[1];
    if (lane == 0) out[row] = (t >= 0.0) ? c0 : c1;
  }
}

extern "C" void kernel_launch(void* const* d_in, const int* in_sizes, int n_in,
                              void* d_out, int out_size, void* d_ws, size_t ws_size,
                              hipStream_t stream) {
  const float* x     = (const float*)d_in[0];
  const float* w_out = (const float*)d_in[1];
  const float* b_out = (const float*)d_in[2];
  const float* w_cat = (const float*)d_in[3];
  const float* b_cat = (const float*)d_in[4];
  const float* w2    = (const float*)d_in[5];
  const float* b2    = (const float*)d_in[6];
  float* out = (float*)d_out;

  const int N = in_sizes[0] / DIN;       // 524288
  const int nblk = N / (4 * NG * 16);    // 512 blocks x 1024 rows

  if (ws_size >= (size_t)N * sizeof(float)) {
    float* dws = (float*)d_ws;
    entmax_sign_mfma<true><<<nblk, 256, 0, stream>>>(x, w_out, b_out, w_cat,
                                                     b_cat, w2, b2, out, dws);
    entmax_fixup<<<N / 256, 256, 0, stream>>>(x, w_out, b_out, w_cat, b_cat,
                                              w2, b2, out, dws);
  } else {
    entmax_sign_mfma<false><<<nblk, 256, 0, stream>>>(x, w_out, b_out, w_cat,
                                                      b_cat, w2, b2, out, nullptr);
  }
}